// Round 1
// baseline (1693.679 us; speedup 1.0000x reference)
//
#include <hip/hip_runtime.h>

#define N_NODES 100000
#define N_EDGES 3200000
#define ALPHA   0.1f
#define ITERS   10

// ---------------------------------------------------------------------------
// Fused MLP: z = relu(F @ W1 + b1) @ W2 + b2
// Block = 256 threads handles 16 rows. Features staged in LDS (32KB),
// each thread computes 4 rows x 1 col with register accumulators.
// ---------------------------------------------------------------------------
__global__ __launch_bounds__(256) void mlp_kernel(
    const float* __restrict__ f, const float* __restrict__ W1,
    const float* __restrict__ b1, const float* __restrict__ W2,
    const float* __restrict__ b2, float* __restrict__ z)
{
    __shared__ float fs[16 * 512];
    __shared__ float hs[16 * 64];
    const int tid = threadIdx.x;
    const int j   = tid & 63;   // output column
    const int rg  = tid >> 6;   // row group 0..3
    const long base = (long)blockIdx.x * 16;

    // stage 16 feature rows (32KB) coalesced as float4
    const float4* src = (const float4*)(f + base * 512);
    float4* dst = (float4*)fs;
#pragma unroll
    for (int i = 0; i < 8; ++i) dst[i * 256 + tid] = src[i * 256 + tid];
    __syncthreads();

    float b = b1[j];
    float acc0 = b, acc1 = b, acc2 = b, acc3 = b;
    const float* fr0 = fs + (rg * 4 + 0) * 512;
    const float* fr1 = fs + (rg * 4 + 1) * 512;
    const float* fr2 = fs + (rg * 4 + 2) * 512;
    const float* fr3 = fs + (rg * 4 + 3) * 512;

    for (int k = 0; k < 512; k += 4) {
        float w0 = W1[(k + 0) * 64 + j];
        float w1v = W1[(k + 1) * 64 + j];
        float w2v = W1[(k + 2) * 64 + j];
        float w3v = W1[(k + 3) * 64 + j];
        float4 a0 = *(const float4*)(fr0 + k);
        float4 a1 = *(const float4*)(fr1 + k);
        float4 a2 = *(const float4*)(fr2 + k);
        float4 a3 = *(const float4*)(fr3 + k);
        acc0 += a0.x * w0 + a0.y * w1v + a0.z * w2v + a0.w * w3v;
        acc1 += a1.x * w0 + a1.y * w1v + a1.z * w2v + a1.w * w3v;
        acc2 += a2.x * w0 + a2.y * w1v + a2.z * w2v + a2.w * w3v;
        acc3 += a3.x * w0 + a3.y * w1v + a3.z * w2v + a3.w * w3v;
    }
    hs[(rg * 4 + 0) * 64 + j] = fmaxf(acc0, 0.0f);
    hs[(rg * 4 + 1) * 64 + j] = fmaxf(acc1, 0.0f);
    hs[(rg * 4 + 2) * 64 + j] = fmaxf(acc2, 0.0f);
    hs[(rg * 4 + 3) * 64 + j] = fmaxf(acc3, 0.0f);
    __syncthreads();

    float bb = b2[j];
    float o0 = bb, o1 = bb, o2 = bb, o3 = bb;
    const float* h0 = hs + (rg * 4 + 0) * 64;
    const float* h1 = hs + (rg * 4 + 1) * 64;
    const float* h2 = hs + (rg * 4 + 2) * 64;
    const float* h3 = hs + (rg * 4 + 3) * 64;
    for (int k = 0; k < 64; k += 4) {
        float w0 = W2[(k + 0) * 64 + j];
        float w1v = W2[(k + 1) * 64 + j];
        float w2v = W2[(k + 2) * 64 + j];
        float w3v = W2[(k + 3) * 64 + j];
        float4 a0 = *(const float4*)(h0 + k);
        float4 a1 = *(const float4*)(h1 + k);
        float4 a2 = *(const float4*)(h2 + k);
        float4 a3 = *(const float4*)(h3 + k);
        o0 += a0.x * w0 + a0.y * w1v + a0.z * w2v + a0.w * w3v;
        o1 += a1.x * w0 + a1.y * w1v + a1.z * w2v + a1.w * w3v;
        o2 += a2.x * w0 + a2.y * w1v + a2.z * w2v + a2.w * w3v;
        o3 += a3.x * w0 + a3.y * w1v + a3.z * w2v + a3.w * w3v;
    }
    z[(base + rg * 4 + 0) * 64 + j] = o0;
    z[(base + rg * 4 + 1) * 64 + j] = o1;
    z[(base + rg * 4 + 2) * 64 + j] = o2;
    z[(base + rg * 4 + 3) * 64 + j] = o3;
}

// ---------------------------------------------------------------------------
// CSR build (keyed by destination row): histogram -> scan -> stable-ish scatter
// ---------------------------------------------------------------------------
__global__ void hist_kernel(const int* __restrict__ rows, int* __restrict__ deg, int E)
{
    int i = blockIdx.x * blockDim.x + threadIdx.x;
    if (i < E) atomicAdd(&deg[rows[i]], 1);
}

__global__ void block_sum_kernel(const int* __restrict__ deg, int* __restrict__ bsum, int N)
{
    __shared__ int s[256];
    int g = blockIdx.x * 256 + threadIdx.x;
    s[threadIdx.x] = (g < N) ? deg[g] : 0;
    __syncthreads();
    for (int off = 128; off > 0; off >>= 1) {
        if (threadIdx.x < off) s[threadIdx.x] += s[threadIdx.x + off];
        __syncthreads();
    }
    if (threadIdx.x == 0) bsum[blockIdx.x] = s[0];
}

__global__ void scan_bsum_kernel(const int* __restrict__ bsum, int* __restrict__ boff, int nb)
{
    if (threadIdx.x == 0 && blockIdx.x == 0) {
        int run = 0;
        for (int i = 0; i < nb; ++i) { boff[i] = run; run += bsum[i]; }
    }
}

__global__ void scan_chunks_kernel(const int* __restrict__ deg, const int* __restrict__ boff,
                                   int* __restrict__ row_ptr, int* __restrict__ cursor, int N)
{
    __shared__ int s[256];
    int tid = threadIdx.x;
    int g = blockIdx.x * 256 + tid;
    int v = (g < N) ? deg[g] : 0;
    s[tid] = v;
    __syncthreads();
    for (int off = 1; off < 256; off <<= 1) {
        int t = (tid >= off) ? s[tid - off] : 0;
        __syncthreads();
        s[tid] += t;
        __syncthreads();
    }
    int incl = s[tid];
    if (g < N) {
        int rp = boff[blockIdx.x] + incl - v;
        row_ptr[g] = rp;
        cursor[g]  = rp;
    }
    if (g == N - 1) row_ptr[N] = boff[blockIdx.x] + incl;
}

__global__ void scatter_kernel(const int* __restrict__ rows, const int* __restrict__ cols,
                               const float* __restrict__ w, int* __restrict__ cursor,
                               int* __restrict__ colS, float* __restrict__ wS, int E)
{
    int i = blockIdx.x * blockDim.x + threadIdx.x;
    if (i < E) {
        int r = rows[i];
        int pos = atomicAdd(&cursor[r], 1);
        colS[pos] = cols[i];
        wS[pos]   = w[i];
    }
}

// ---------------------------------------------------------------------------
// SpMM + APPNP update: pout[r] = (1-a) * sum_e w_e * pin[col_e] + a * z[r]
// One wave per row; 16 lanes x float4 per edge, 4 edges in flight.
// ---------------------------------------------------------------------------
__global__ __launch_bounds__(256) void spmm_kernel(
    const int* __restrict__ row_ptr, const int* __restrict__ cols,
    const float* __restrict__ w, const float* __restrict__ pin,
    const float* __restrict__ z, float* __restrict__ pout)
{
    const int wid = blockIdx.x * 4 + (threadIdx.x >> 6);
    if (wid >= N_NODES) return;
    const int lane = threadIdx.x & 63;
    const int sub  = lane >> 4;   // edge sub-slot 0..3
    const int l16  = lane & 15;   // label quad 0..15

    const int start = row_ptr[wid];
    const int end   = row_ptr[wid + 1];

    float4 acc = make_float4(0.f, 0.f, 0.f, 0.f);
    for (int e = start + sub; e < end; e += 4) {
        const int   c  = cols[e];
        const float ww = w[e];
        float4 v = *(const float4*)(pin + (long)c * 64 + l16 * 4);
        acc.x += ww * v.x;
        acc.y += ww * v.y;
        acc.z += ww * v.z;
        acc.w += ww * v.w;
    }
    // combine the 4 edge sub-slots (lanes l, l^16, l^32, l^48)
    acc.x += __shfl_xor(acc.x, 16); acc.y += __shfl_xor(acc.y, 16);
    acc.z += __shfl_xor(acc.z, 16); acc.w += __shfl_xor(acc.w, 16);
    acc.x += __shfl_xor(acc.x, 32); acc.y += __shfl_xor(acc.y, 32);
    acc.z += __shfl_xor(acc.z, 32); acc.w += __shfl_xor(acc.w, 32);

    if (sub == 0) {
        float4 zv = *(const float4*)(z + (long)wid * 64 + l16 * 4);
        float4 o;
        o.x = (1.0f - ALPHA) * acc.x + ALPHA * zv.x;
        o.y = (1.0f - ALPHA) * acc.y + ALPHA * zv.y;
        o.z = (1.0f - ALPHA) * acc.z + ALPHA * zv.z;
        o.w = (1.0f - ALPHA) * acc.w + ALPHA * zv.w;
        *(float4*)(pout + (long)wid * 64 + l16 * 4) = o;
    }
}

// ---------------------------------------------------------------------------
extern "C" void kernel_launch(void* const* d_in, const int* in_sizes, int n_in,
                              void* d_out, int out_size, void* d_ws, size_t ws_size,
                              hipStream_t stream)
{
    const float* features = (const float*)d_in[0];
    const float* W1 = (const float*)d_in[1];
    const float* b1 = (const float*)d_in[2];
    const float* W2 = (const float*)d_in[3];
    const float* b2 = (const float*)d_in[4];
    const float* ew = (const float*)d_in[5];
    const int*   ei = (const int*)d_in[6];       // [2][E] int32
    const int* erow = ei;
    const int* ecol = ei + N_EDGES;
    float* out = (float*)d_out;

    char* ws = (char*)d_ws;
    size_t off = 0;
    auto alloc = [&](size_t bytes) {
        size_t c = off;
        off += (bytes + 255) & ~(size_t)255;
        return c;
    };
    float* z      = (float*)(ws + alloc((size_t)N_NODES * 64 * 4));
    float* ptmp   = (float*)(ws + alloc((size_t)N_NODES * 64 * 4));
    int*   colS   = (int*)  (ws + alloc((size_t)N_EDGES * 4));
    float* wS     = (float*)(ws + alloc((size_t)N_EDGES * 4));
    int*   deg    = (int*)  (ws + alloc((size_t)N_NODES * 4));
    int*   rowp   = (int*)  (ws + alloc((size_t)(N_NODES + 1) * 4));
    int*   cursor = (int*)  (ws + alloc((size_t)N_NODES * 4));
    int*   bsum   = (int*)  (ws + alloc((size_t)512 * 4));
    int*   boff   = (int*)  (ws + alloc((size_t)512 * 4));
    (void)ws_size; (void)in_sizes; (void)n_in; (void)out_size;

    // 1) MLP head -> z
    mlp_kernel<<<N_NODES / 16, 256, 0, stream>>>(features, W1, b1, W2, b2, z);

    // 2) CSR build (by destination row)
    hipMemsetAsync(deg, 0, (size_t)N_NODES * 4, stream);
    hist_kernel<<<(N_EDGES + 255) / 256, 256, 0, stream>>>(erow, deg, N_EDGES);
    const int nb = (N_NODES + 255) / 256;  // 391
    block_sum_kernel<<<nb, 256, 0, stream>>>(deg, bsum, N_NODES);
    scan_bsum_kernel<<<1, 64, 0, stream>>>(bsum, boff, nb);
    scan_chunks_kernel<<<nb, 256, 0, stream>>>(deg, boff, rowp, cursor, N_NODES);
    scatter_kernel<<<(N_EDGES + 255) / 256, 256, 0, stream>>>(erow, ecol, ew, cursor, colS, wS, N_EDGES);

    // 3) 10 propagation iterations; even count ends in d_out
    const float* pin = z;
    for (int it = 1; it <= ITERS; ++it) {
        float* pout = (it & 1) ? ptmp : out;
        spmm_kernel<<<(N_NODES + 3) / 4, 256, 0, stream>>>(rowp, colS, wS, pin, z, pout);
        pin = pout;
    }
}

// Round 3
// 1380.870 us; speedup vs baseline: 1.2265x; 1.2265x over previous
//
#include <hip/hip_runtime.h>
#include <hip/hip_fp16.h>
#include <cmath>

#define N_NODES 100000
#define N_EDGES 3200000
#define ALPHA   0.1f
#define ITERS   10

typedef __attribute__((ext_vector_type(8))) short short8;
typedef __attribute__((ext_vector_type(4))) short short4v;
typedef __attribute__((ext_vector_type(4))) float f32x4;

__device__ __forceinline__ short f2bf(float x) {
    union { float f; unsigned u; } v; v.f = x;
    unsigned r = v.u + 0x7fffu + ((v.u >> 16) & 1u);   // RNE
    return (short)(r >> 16);
}

// ---------------------------------------------------------------------------
// One-time weight prep: W1[512][64] -> W1t[64][512] bf16 ; W2[64][64] -> W2t[64][64] bf16
// ---------------------------------------------------------------------------
__global__ void prep_w(const float* __restrict__ W1, const float* __restrict__ W2,
                       short* __restrict__ W1t, short* __restrict__ W2t)
{
    int t = blockIdx.x * 256 + threadIdx.x;
    if (t < 512 * 64) { int k = t >> 6, c = t & 63; W1t[c * 512 + k] = f2bf(W1[t]); }
    if (t < 64 * 64)  { int k = t >> 6, c = t & 63; W2t[c * 64 + k]  = f2bf(W2[t]); }
}

// ---------------------------------------------------------------------------
// Fused MFMA MLP: z = relu(F @ W1 + b1) @ W2 + b2   (also writes q0 = fp16(z))
// Block = 256 threads = 4 waves, 64 rows. bf16 16x16x32 MFMA.
// LDS tiles XOR-swizzled: short idx ^ ((row&7)<<3) -> conflict-free ds_read_b128.
// ---------------------------------------------------------------------------
__global__ __launch_bounds__(256) void mlp_mfma(
    const float* __restrict__ F, const short* __restrict__ W1t,
    const short* __restrict__ W2t, const float* __restrict__ b1,
    const float* __restrict__ b2, float* __restrict__ z, __half* __restrict__ q0)
{
    __shared__ short Ft[64 * 128];   // 16KB feature tile (bf16, swizzled)
    __shared__ short Wt[64 * 128];   // 16KB W1t tile [col][k]
    __shared__ short Ht[64 * 64];    // 8KB hidden (bf16, swizzled)
    __shared__ short W2s[64 * 64];   // 8KB W2t [col][k]

    const int t  = threadIdx.x;
    const int l  = t & 63;
    const int wv = t >> 6;          // wave 0..3
    const int wr = wv * 16;         // wave's row base within tile
    const long base = (long)blockIdx.x * 64;

    f32x4 acc[4] = {};
    for (int kt = 0; kt < 4; ++kt) {
        // stage F tile (64 rows x 128 k), f32 -> bf16, swizzled (8192 shorts)
#pragma unroll
        for (int j = 0; j < 8; ++j) {
            int idx4 = (t + 256 * j) * 4;          // element index in tile
            int row = idx4 >> 7, k = idx4 & 127;
            long grow = base + row; if (grow > N_NODES - 1) grow = N_NODES - 1;
            float4 v = *(const float4*)(F + grow * 512 + kt * 128 + k);
            short4v s = { f2bf(v.x), f2bf(v.y), f2bf(v.z), f2bf(v.w) };
            *(short4v*)&Ft[(row * 128 + k) ^ ((row & 7) << 3)] = s;
        }
        // stage W1t tile (64 cols x 128 k) bf16 (8192 shorts, 4 per op -> j<8)
#pragma unroll
        for (int j = 0; j < 8; ++j) {
            int h4 = (t + 256 * j) * 4;
            int row = h4 >> 7, k = h4 & 127;
            uint2 v = *(const uint2*)(W1t + row * 512 + kt * 128 + k);
            *(uint2*)&Wt[(row * 128 + k) ^ ((row & 7) << 3)] = v;
        }
        if (kt == 0) {
            // 64x64 = 4096 shorts, 4 per op -> j<4
#pragma unroll
            for (int j = 0; j < 4; ++j) {
                int h4 = (t + 256 * j) * 4;
                int row = h4 >> 6, k = h4 & 63;
                uint2 v = *(const uint2*)(W2t + row * 64 + k);
                *(uint2*)&W2s[(row * 64 + k) ^ ((row & 7) << 3)] = v;
            }
        }
        __syncthreads();
#pragma unroll
        for (int kc = 0; kc < 4; ++kc) {
            int kb = kc * 32 + (l >> 4) * 8;
            int ar = wr + (l & 15);
            short8 a = *(const short8*)&Ft[(ar * 128 + kb) ^ ((ar & 7) << 3)];
#pragma unroll
            for (int n = 0; n < 4; ++n) {
                int bc = n * 16 + (l & 15);
                short8 b = *(const short8*)&Wt[(bc * 128 + kb) ^ ((bc & 7) << 3)];
                acc[n] = __builtin_amdgcn_mfma_f32_16x16x32_bf16(a, b, acc[n], 0, 0, 0);
            }
        }
        __syncthreads();
    }

    // relu(acc + b1) -> Ht (each wave writes only its own 16 rows)
#pragma unroll
    for (int n = 0; n < 4; ++n) {
        int col = n * 16 + (l & 15);
        float bv = b1[col];
#pragma unroll
        for (int i = 0; i < 4; ++i) {
            int row = wr + (l >> 4) * 4 + i;
            float hv = fmaxf(acc[n][i] + bv, 0.0f);
            Ht[(row * 64 + col) ^ ((row & 7) << 3)] = f2bf(hv);
        }
    }
    // layer 2: each wave reads only its own Ht rows -> no barrier needed
    f32x4 acc2[4] = {};
#pragma unroll
    for (int kc = 0; kc < 2; ++kc) {
        int kb = kc * 32 + (l >> 4) * 8;
        int ar = wr + (l & 15);
        short8 a = *(const short8*)&Ht[(ar * 64 + kb) ^ ((ar & 7) << 3)];
#pragma unroll
        for (int n = 0; n < 4; ++n) {
            int bc = n * 16 + (l & 15);
            short8 b = *(const short8*)&W2s[(bc * 64 + kb) ^ ((bc & 7) << 3)];
            acc2[n] = __builtin_amdgcn_mfma_f32_16x16x32_bf16(a, b, acc2[n], 0, 0, 0);
        }
    }
#pragma unroll
    for (int n = 0; n < 4; ++n) {
        int col = n * 16 + (l & 15);
        float bv = b2[col];
#pragma unroll
        for (int i = 0; i < 4; ++i) {
            long row = base + wr + (l >> 4) * 4 + i;
            if (row < N_NODES) {
                float zv = acc2[n][i] + bv;
                z[row * 64 + col]  = zv;
                q0[row * 64 + col] = __float2half(zv);
            }
        }
    }
}

// ---------------------------------------------------------------------------
// CSR build
// ---------------------------------------------------------------------------
__global__ void hist_kernel(const int* __restrict__ rows, int* __restrict__ deg, int E)
{
    int i = blockIdx.x * blockDim.x + threadIdx.x;
    if (i < E) atomicAdd(&deg[rows[i]], 1);
}

__global__ void block_sum_kernel(const int* __restrict__ deg, int* __restrict__ bsum, int N)
{
    __shared__ int s[256];
    int g = blockIdx.x * 256 + threadIdx.x;
    s[threadIdx.x] = (g < N) ? deg[g] : 0;
    __syncthreads();
    for (int off = 128; off > 0; off >>= 1) {
        if (threadIdx.x < off) s[threadIdx.x] += s[threadIdx.x + off];
        __syncthreads();
    }
    if (threadIdx.x == 0) bsum[blockIdx.x] = s[0];
}

// one-block parallel exclusive scan of the 391 block sums
__global__ void scan_bsum_kernel(const int* __restrict__ bsum, int* __restrict__ boff, int nb)
{
    __shared__ int s[512];
    int t = threadIdx.x;
    int v = (t < nb) ? bsum[t] : 0;
    s[t] = v;
    __syncthreads();
    for (int off = 1; off < 512; off <<= 1) {
        int x = (t >= off) ? s[t - off] : 0;
        __syncthreads();
        s[t] += x;
        __syncthreads();
    }
    if (t < nb) boff[t] = s[t] - v;   // exclusive
}

__global__ void scan_chunks_kernel(const int* __restrict__ deg, const int* __restrict__ boff,
                                   int* __restrict__ row_ptr, int* __restrict__ cursor, int N)
{
    __shared__ int s[256];
    int tid = threadIdx.x;
    int g = blockIdx.x * 256 + tid;
    int v = (g < N) ? deg[g] : 0;
    s[tid] = v;
    __syncthreads();
    for (int off = 1; off < 256; off <<= 1) {
        int x = (tid >= off) ? s[tid - off] : 0;
        __syncthreads();
        s[tid] += x;
        __syncthreads();
    }
    int incl = s[tid];
    if (g < N) {
        int rp = boff[blockIdx.x] + incl - v;
        row_ptr[g] = rp;
        cursor[g]  = rp;
    }
    if (g == N - 1) row_ptr[N] = boff[blockIdx.x] + incl;
}

// scatter: pack (col, w * (1-ALPHA)/16) into one 8B word
__global__ void scatter_kernel(const int* __restrict__ rows, const int* __restrict__ cols,
                               const float* __restrict__ w, int* __restrict__ cursor,
                               unsigned long long* __restrict__ cw, int E)
{
    int i = blockIdx.x * blockDim.x + threadIdx.x;
    if (i < E) {
        int r = rows[i];
        int pos = atomicAdd(&cursor[r], 1);
        float ws = w[i] * ((1.0f - ALPHA) / 16.0f);
        unsigned wb = __float_as_uint(ws);
        cw[pos] = (unsigned long long)(unsigned)cols[i] | ((unsigned long long)wb << 32);
    }
}

// ---------------------------------------------------------------------------
// SpMM on scaled fp16 state: q_t = sum w' * q_{t-1}[col] + beta_t * z
// LAST: out = outscale * q_10 (fp32)
// One wave per row; 16 lanes x 4 labels (8B gather), 4 edges in flight.
// ---------------------------------------------------------------------------
template <int LAST>
__global__ __launch_bounds__(256) void spmm_kernel(
    const int* __restrict__ rowp, const unsigned long long* __restrict__ cw,
    const __half* __restrict__ qin, const float* __restrict__ z,
    float beta, float outscale,
    __half* __restrict__ qout, float* __restrict__ out)
{
    const int wid = blockIdx.x * 4 + (threadIdx.x >> 6);
    if (wid >= N_NODES) return;
    const int lane = threadIdx.x & 63;
    const int sub  = lane >> 4;
    const int l16  = lane & 15;

    const int start = rowp[wid];
    const int end   = rowp[wid + 1];

    float ax = 0.f, ay = 0.f, az = 0.f, aw = 0.f;
    for (int e = start + sub; e < end; e += 4) {
        unsigned long long pc = cw[e];
        int   c  = (int)(unsigned)pc;
        float ww = __uint_as_float((unsigned)(pc >> 32));
        uint2 v = *(const uint2*)(qin + (long)c * 64 + l16 * 4);
        __half2 h0 = *reinterpret_cast<__half2*>(&v.x);
        __half2 h1 = *reinterpret_cast<__half2*>(&v.y);
        float2 f0 = __half22float2(h0);
        float2 f1 = __half22float2(h1);
        ax += ww * f0.x; ay += ww * f0.y; az += ww * f1.x; aw += ww * f1.y;
    }
    ax += __shfl_xor(ax, 16); ay += __shfl_xor(ay, 16);
    az += __shfl_xor(az, 16); aw += __shfl_xor(aw, 16);
    ax += __shfl_xor(ax, 32); ay += __shfl_xor(ay, 32);
    az += __shfl_xor(az, 32); aw += __shfl_xor(aw, 32);

    if (sub == 0) {
        float4 zv = *(const float4*)(z + (long)wid * 64 + l16 * 4);
        float ox = ax + beta * zv.x;
        float oy = ay + beta * zv.y;
        float oz = az + beta * zv.z;
        float ow = aw + beta * zv.w;
        if (LAST) {
            float4 o = { outscale * ox, outscale * oy, outscale * oz, outscale * ow };
            *(float4*)(out + (long)wid * 64 + l16 * 4) = o;
        } else {
            __half2 p0 = __floats2half2_rn(ox, oy);
            __half2 p1 = __floats2half2_rn(oz, ow);
            uint2 pv = { *(unsigned*)&p0, *(unsigned*)&p1 };
            *(uint2*)(qout + (long)wid * 64 + l16 * 4) = pv;
        }
    }
}

// ---------------------------------------------------------------------------
extern "C" void kernel_launch(void* const* d_in, const int* in_sizes, int n_in,
                              void* d_out, int out_size, void* d_ws, size_t ws_size,
                              hipStream_t stream)
{
    const float* features = (const float*)d_in[0];
    const float* W1 = (const float*)d_in[1];
    const float* b1 = (const float*)d_in[2];
    const float* W2 = (const float*)d_in[3];
    const float* b2 = (const float*)d_in[4];
    const float* ew = (const float*)d_in[5];
    const int*   ei = (const int*)d_in[6];
    const int* erow = ei;
    const int* ecol = ei + N_EDGES;
    float* out = (float*)d_out;

    char* ws = (char*)d_ws;
    size_t off = 0;
    auto alloc = [&](size_t bytes) {
        size_t c = off;
        off += (bytes + 255) & ~(size_t)255;
        return c;
    };
    float* z      = (float*)(ws + alloc((size_t)N_NODES * 64 * 4));
    __half* q0    = (__half*)(ws + alloc((size_t)N_NODES * 64 * 2));
    __half* qA    = (__half*)(ws + alloc((size_t)N_NODES * 64 * 2));
    unsigned long long* cw = (unsigned long long*)(ws + alloc((size_t)N_EDGES * 8));
    short* W1t    = (short*)(ws + alloc((size_t)512 * 64 * 2));
    short* W2t    = (short*)(ws + alloc((size_t)64 * 64 * 2));
    int*   deg    = (int*)  (ws + alloc((size_t)N_NODES * 4));
    int*   rowp   = (int*)  (ws + alloc((size_t)(N_NODES + 1) * 4));
    int*   cursor = (int*)  (ws + alloc((size_t)N_NODES * 4));
    int*   bsum   = (int*)  (ws + alloc((size_t)512 * 4));
    int*   boff   = (int*)  (ws + alloc((size_t)512 * 4));
    (void)ws_size; (void)in_sizes; (void)n_in; (void)out_size;

    // 1) weight prep + MLP head (writes z fp32 and q0 fp16)
    prep_w<<<128, 256, 0, stream>>>(W1, W2, W1t, W2t);
    mlp_mfma<<<(N_NODES + 63) / 64, 256, 0, stream>>>(features, W1t, W2t, b1, b2, z, q0);

    // 2) CSR build keyed by destination row
    hipMemsetAsync(deg, 0, (size_t)N_NODES * 4, stream);
    hist_kernel<<<(N_EDGES + 255) / 256, 256, 0, stream>>>(erow, deg, N_EDGES);
    const int nb = (N_NODES + 255) / 256;  // 391
    block_sum_kernel<<<nb, 256, 0, stream>>>(deg, bsum, N_NODES);
    scan_bsum_kernel<<<1, 512, 0, stream>>>(bsum, boff, nb);
    scan_chunks_kernel<<<nb, 256, 0, stream>>>(deg, boff, rowp, cursor, N_NODES);
    scatter_kernel<<<(N_EDGES + 255) / 256, 256, 0, stream>>>(erow, ecol, ew, cursor, cw, N_EDGES);

    // 3) 10 propagation iterations on scaled fp16 state (c = 16)
    const __half* qi = q0;
    for (int it = 1; it < ITERS; ++it) {
        __half* qo = (it & 1) ? qA : q0;
        float beta = (float)(0.1 / pow(16.0, (double)it));
        spmm_kernel<0><<<(N_NODES + 3) / 4, 256, 0, stream>>>(rowp, cw, qi, z, beta, 1.0f, qo, nullptr);
        qi = qo;
    }
    float beta10 = (float)(0.1 / pow(16.0, 10.0));
    float osc    = (float)pow(16.0, 10.0);
    spmm_kernel<1><<<(N_NODES + 3) / 4, 256, 0, stream>>>(rowp, cw, qi, z, beta10, osc, nullptr, out);
}